// Round 16
// baseline (148.617 us; speedup 1.0000x reference)
//
#include <hip/hip_runtime.h>
#include <math.h>

#define NEGM (-1e30f)

typedef __fp16 f16x4 __attribute__((ext_vector_type(4)));
typedef __fp16 f16x2 __attribute__((ext_vector_type(2)));
typedef float  f32x4 __attribute__((ext_vector_type(4)));

__device__ __forceinline__ float4 ld4(const float* p) { return *(const float4*)p; }
__device__ __forceinline__ void fma4(float4& a, float s, const float4 w) {
    a.x += s * w.x; a.y += s * w.y; a.z += s * w.z; a.w += s * w.w;
}

// ---------------- Kernel 1: nested-attention history path ----------------
// One wave per TWO rows: two independent dependency chains interleaved in
// one instruction stream -> SIMD overlaps them, halving exposed latency.
// Phase A is MFMA 16x16x16 f16 (R15 structure), duplicated per row.
__global__ __launch_bounds__(64) void hist_kernel(
    const float* __restrict__ x_kicks,
    const float* __restrict__ W_ke, const float* __restrict__ b_ke,
    const float* __restrict__ q_inner,
    const float* __restrict__ W_ge, const float* __restrict__ b_ge,
    const float* __restrict__ pos_emb, const float* __restrict__ q_outer,
    const float* __restrict__ log_temp,
    const float* __restrict__ ln_g, const float* __restrict__ ln_b,
    const int* __restrict__ outer_mask, const int* __restrict__ inner_mask,
    float* __restrict__ hist)
{
    __shared__ float s_wge[512];      // W_ge [16][32]
    __shared__ float s_qout[256];     // q_outer [8][32]
    __shared__ float pg[2][17 * 20];  // per_game, stride 20
    __shared__ float enc[2][17 * 36]; // encoded, stride 36
    __shared__ float ao[2][136];      // outer scores -> weights
    __shared__ float s_S[2][20];      // per-game softmax denominators

    const int lane = threadIdx.x;     // 0..63
    const int b0   = blockIdx.x * 2;  // rows b0, b0+1
    const int jcol = lane & 15;       // MFMA col / A-row sel
    const int g    = lane >> 4;       // k-group
    const int kb   = g * 4;           // k base

    // stage B-E weights
    *(float4*)&s_wge[lane * 4]       = ld4(W_ge + lane * 4);
    *(float4*)&s_wge[256 + lane * 4] = ld4(W_ge + 256 + lane * 4);
    *(float4*)&s_qout[lane * 4]      = ld4(q_outer + lane * 4);

    // per-lane constant fragments (shared by both rows)
    f16x4 bw;
    #pragma unroll
    for (int jj = 0; jj < 4; ++jj)
        bw[jj] = (__fp16)W_ke[(kb + jj) * 16 + jcol];
    const float bias = b_ke[jcol];
    const f32x4 cinit = {bias, bias, bias, bias};
    const float qv = q_inner[jcol];

    const float* xb0 = x_kicks + (size_t)b0 * 204 * 16;
    const float* xb1 = xb0 + 204 * 16;
    const int*   mb0 = inner_mask + (size_t)b0 * 204;
    const int*   mb1 = mb0 + 204;

    f32x4 PG0 = {0,0,0,0}, PG1 = PG0, PGa = PG0, PGb = PG0;  // PGa/PGb: game16 accums
    float Sacc0 = 0.f, Sacc1 = 0.f, S16a = 0.f, S16b = 0.f;

    // ---------- tiles 0..11 : games 0..15, both rows interleaved ----------
    #pragma unroll 2
    for (int t = 0; t < 12; ++t) {
        float4 xv0 = ld4(xb0 + (16 * t + jcol) * 16 + kb);
        float4 xv1 = ld4(xb1 + (16 * t + jcol) * 16 + kb);
        int4 mv0 = *(const int4*)(mb0 + 16 * t + 4 * g);
        int4 mv1 = *(const int4*)(mb1 + 16 * t + 4 * g);

        f16x2 l0 = __builtin_amdgcn_cvt_pkrtz(xv0.x, xv0.y);
        f16x2 h0 = __builtin_amdgcn_cvt_pkrtz(xv0.z, xv0.w);
        f16x4 ax0; ax0[0]=l0[0]; ax0[1]=l0[1]; ax0[2]=h0[0]; ax0[3]=h0[1];
        f16x2 l1 = __builtin_amdgcn_cvt_pkrtz(xv1.x, xv1.y);
        f16x2 h1 = __builtin_amdgcn_cvt_pkrtz(xv1.z, xv1.w);
        f16x4 ax1; ax1[0]=l1[0]; ax1[1]=l1[1]; ax1[2]=h1[0]; ax1[3]=h1[1];

        f32x4 D0 = __builtin_amdgcn_mfma_f32_16x16x16f16(ax0, bw, cinit, 0, 0, 0);
        f32x4 D1 = __builtin_amdgcn_mfma_f32_16x16x16f16(ax1, bw, cinit, 0, 0, 0);
        #pragma unroll
        for (int jj = 0; jj < 4; ++jj) {
            D0[jj] = fmaxf(D0[jj], 0.f);
            D1[jj] = fmaxf(D1[jj], 0.f);
        }

        f32x4 p0, p1;
        #pragma unroll
        for (int jj = 0; jj < 4; ++jj) { p0[jj] = D0[jj] * qv; p1[jj] = D1[jj] * qv; }
        #pragma unroll
        for (int o = 1; o < 16; o <<= 1) {
            p0[0] += __shfl_xor(p0[0], o); p1[0] += __shfl_xor(p1[0], o);
            p0[1] += __shfl_xor(p0[1], o); p1[1] += __shfl_xor(p1[1], o);
            p0[2] += __shfl_xor(p0[2], o); p1[2] += __shfl_xor(p1[2], o);
            p0[3] += __shfl_xor(p0[3], o); p1[3] += __shfl_xor(p1[3], o);
        }

        f16x4 aw0, aw1;
        #pragma unroll
        for (int jj = 0; jj < 4; ++jj) {
            int kk = 16 * t + 4 * g + jj;
            int m0 = (jj==0)?mv0.x:(jj==1)?mv0.y:(jj==2)?mv0.z:mv0.w;
            int m1 = (jj==0)?mv1.x:(jj==1)?mv1.y:(jj==2)?mv1.z:mv1.w;
            float e0 = m0 ? __expf(p0[jj] * 0.25f) : 0.f;
            float e1 = m1 ? __expf(p1[jj] * 0.25f) : 0.f;
            float w0 = (kk / 12 == jcol) ? e0 : 0.f;
            float w1 = (kk / 12 == jcol) ? e1 : 0.f;
            aw0[jj] = (__fp16)w0; aw1[jj] = (__fp16)w1;
            Sacc0 += w0; Sacc1 += w1;
        }

        f16x2 e0l = __builtin_amdgcn_cvt_pkrtz(D0[0], D0[1]);
        f16x2 e0h = __builtin_amdgcn_cvt_pkrtz(D0[2], D0[3]);
        f16x4 be0; be0[0]=e0l[0]; be0[1]=e0l[1]; be0[2]=e0h[0]; be0[3]=e0h[1];
        f16x2 e1l = __builtin_amdgcn_cvt_pkrtz(D1[0], D1[1]);
        f16x2 e1h = __builtin_amdgcn_cvt_pkrtz(D1[2], D1[3]);
        f16x4 be1; be1[0]=e1l[0]; be1[1]=e1l[1]; be1[2]=e1h[0]; be1[3]=e1h[1];

        PG0 = __builtin_amdgcn_mfma_f32_16x16x16f16(aw0, be0, PG0, 0, 0, 0);
        PG1 = __builtin_amdgcn_mfma_f32_16x16x16f16(aw1, be1, PG1, 0, 0, 0);
    }

    // ---------- tile 12 : game 16 (kicks 192..203), both rows ----------
    {
        int kidx = 192 + jcol;
        int kc = (kidx < 204) ? kidx : 203;
        float4 xv0 = ld4(xb0 + kc * 16 + kb);
        float4 xv1 = ld4(xb1 + kc * 16 + kb);
        int km = 192 + 4 * g;
        int kmc = (km <= 200) ? km : 200;
        int4 mv0 = *(const int4*)(mb0 + kmc);
        int4 mv1 = *(const int4*)(mb1 + kmc);

        f16x2 l0 = __builtin_amdgcn_cvt_pkrtz(xv0.x, xv0.y);
        f16x2 h0 = __builtin_amdgcn_cvt_pkrtz(xv0.z, xv0.w);
        f16x4 ax0; ax0[0]=l0[0]; ax0[1]=l0[1]; ax0[2]=h0[0]; ax0[3]=h0[1];
        f16x2 l1 = __builtin_amdgcn_cvt_pkrtz(xv1.x, xv1.y);
        f16x2 h1 = __builtin_amdgcn_cvt_pkrtz(xv1.z, xv1.w);
        f16x4 ax1; ax1[0]=l1[0]; ax1[1]=l1[1]; ax1[2]=h1[0]; ax1[3]=h1[1];

        f32x4 D0 = __builtin_amdgcn_mfma_f32_16x16x16f16(ax0, bw, cinit, 0, 0, 0);
        f32x4 D1 = __builtin_amdgcn_mfma_f32_16x16x16f16(ax1, bw, cinit, 0, 0, 0);
        #pragma unroll
        for (int jj = 0; jj < 4; ++jj) {
            D0[jj] = fmaxf(D0[jj], 0.f);
            D1[jj] = fmaxf(D1[jj], 0.f);
        }

        f32x4 p0, p1;
        #pragma unroll
        for (int jj = 0; jj < 4; ++jj) { p0[jj] = D0[jj] * qv; p1[jj] = D1[jj] * qv; }
        #pragma unroll
        for (int o = 1; o < 16; o <<= 1) {
            p0[0] += __shfl_xor(p0[0], o); p1[0] += __shfl_xor(p1[0], o);
            p0[1] += __shfl_xor(p0[1], o); p1[1] += __shfl_xor(p1[1], o);
            p0[2] += __shfl_xor(p0[2], o); p1[2] += __shfl_xor(p1[2], o);
            p0[3] += __shfl_xor(p0[3], o); p1[3] += __shfl_xor(p1[3], o);
        }

        f16x4 aw0, aw1;
        #pragma unroll
        for (int jj = 0; jj < 4; ++jj) {
            int pos = 4 * g + jj;
            int m0 = (jj==0)?mv0.x:(jj==1)?mv0.y:(jj==2)?mv0.z:mv0.w;
            int m1 = (jj==0)?mv1.x:(jj==1)?mv1.y:(jj==2)?mv1.z:mv1.w;
            bool va = (pos < 12);
            float e0 = (va && m0) ? __expf(p0[jj] * 0.25f) : 0.f;
            float e1 = (va && m1) ? __expf(p1[jj] * 0.25f) : 0.f;
            float w0 = (jcol == 0) ? e0 : 0.f;
            float w1 = (jcol == 0) ? e1 : 0.f;
            aw0[jj] = (__fp16)w0; aw1[jj] = (__fp16)w1;
            S16a += w0; S16b += w1;
        }

        f16x2 e0l = __builtin_amdgcn_cvt_pkrtz(D0[0], D0[1]);
        f16x2 e0h = __builtin_amdgcn_cvt_pkrtz(D0[2], D0[3]);
        f16x4 be0; be0[0]=e0l[0]; be0[1]=e0l[1]; be0[2]=e0h[0]; be0[3]=e0h[1];
        f16x2 e1l = __builtin_amdgcn_cvt_pkrtz(D1[0], D1[1]);
        f16x2 e1h = __builtin_amdgcn_cvt_pkrtz(D1[2], D1[3]);
        f16x4 be1; be1[0]=e1l[0]; be1[1]=e1l[1]; be1[2]=e1h[0]; be1[3]=e1h[1];

        PGa = __builtin_amdgcn_mfma_f32_16x16x16f16(aw0, be0, PGa, 0, 0, 0);
        PGb = __builtin_amdgcn_mfma_f32_16x16x16f16(aw1, be1, PGb, 0, 0, 0);
    }

    // ---------- denominators & per_game writes ----------
    Sacc0 += __shfl_xor(Sacc0, 16); Sacc1 += __shfl_xor(Sacc1, 16);
    Sacc0 += __shfl_xor(Sacc0, 32); Sacc1 += __shfl_xor(Sacc1, 32);
    S16a += __shfl_xor(S16a, 16);  S16b += __shfl_xor(S16b, 16);
    S16a += __shfl_xor(S16a, 32);  S16b += __shfl_xor(S16b, 32);

    if (lane < 16) { s_S[0][lane] = Sacc0; s_S[1][lane] = Sacc1; }
    if (lane == 0) { s_S[0][16] = S16a; s_S[1][16] = S16b; }
    __syncthreads();

    #pragma unroll
    for (int jj = 0; jj < 4; ++jj) {
        int game = kb + jj;
        pg[0][game * 20 + jcol] = PG0[jj] * (1.f / s_S[0][game]);
        pg[1][game * 20 + jcol] = PG1[jj] * (1.f / s_S[1][game]);
    }
    if (lane < 16) {
        pg[0][16 * 20 + lane] = PGa[0] * (1.f / s_S[0][16]);
        pg[1][16 * 20 + lane] = PGb[0] * (1.f / s_S[1][16]);
    }
    __syncthreads();

    // ---------- Phase B: game encoder + pos emb, both rows ----------
    for (int t = lane; t < 136; t += 64) {
        const int gg = t >> 3, dq = t & 7;
        float4 a0 = ld4(b_ge + dq * 4), a1 = a0;
        #pragma unroll
        for (int i = 0; i < 16; ++i) {
            float4 w = *(float4*)&s_wge[i * 32 + dq * 4];
            fma4(a0, pg[0][gg * 20 + i], w);
            fma4(a1, pg[1][gg * 20 + i], w);
        }
        float4 pe = ld4(pos_emb + gg * 32 + dq * 4);
        a0.x = fmaxf(a0.x,0.f)+pe.x; a0.y = fmaxf(a0.y,0.f)+pe.y;
        a0.z = fmaxf(a0.z,0.f)+pe.z; a0.w = fmaxf(a0.w,0.f)+pe.w;
        a1.x = fmaxf(a1.x,0.f)+pe.x; a1.y = fmaxf(a1.y,0.f)+pe.y;
        a1.z = fmaxf(a1.z,0.f)+pe.z; a1.w = fmaxf(a1.w,0.f)+pe.w;
        *(float4*)&enc[0][gg * 36 + dq * 4] = a0;
        *(float4*)&enc[1][gg * 36 + dq * 4] = a1;
    }
    __syncthreads();

    // ---------- Phase C: outer scores, both rows ----------
    for (int t = lane; t < 136; t += 64) {
        const int q = t / 17, gg = t - q * 17;
        float4 a0 = {0,0,0,0}, a1 = a0;
        #pragma unroll
        for (int i4 = 0; i4 < 8; ++i4) {
            float4 qvv = *(float4*)&s_qout[q * 32 + i4 * 4];
            float4 e0 = *(float4*)&enc[0][gg * 36 + i4 * 4];
            float4 e1 = *(float4*)&enc[1][gg * 36 + i4 * 4];
            a0.x += e0.x*qvv.x; a0.y += e0.y*qvv.y; a0.z += e0.z*qvv.z; a0.w += e0.w*qvv.w;
            a1.x += e1.x*qvv.x; a1.y += e1.y*qvv.y; a1.z += e1.z*qvv.z; a1.w += e1.w*qvv.w;
        }
        float sc = 0.17677669529663687f * __expf(-log_temp[q >> 1]);
        float s0 = ((a0.x+a0.y)+(a0.z+a0.w)) * sc;
        float s1 = ((a1.x+a1.y)+(a1.z+a1.w)) * sc;
        ao[0][t] = outer_mask[(b0 + 0) * 17 + gg] ? s0 : NEGM;
        ao[1][t] = outer_mask[(b0 + 1) * 17 + gg] ? s1 : NEGM;
    }
    __syncthreads();

    // ---------- Phase D: outer softmax, both rows ----------
    #pragma unroll
    for (int r = 0; r < 2; ++r) {
        const int q = lane >> 3, j = lane & 7;
        float s0 = ao[r][q * 17 + j];
        float s1 = ao[r][q * 17 + j + 8];
        float s2 = (j == 0) ? ao[r][q * 17 + 16] : NEGM;
        float mx = fmaxf(fmaxf(s0, s1), s2);
        mx = fmaxf(mx, __shfl_xor(mx, 1));
        mx = fmaxf(mx, __shfl_xor(mx, 2));
        mx = fmaxf(mx, __shfl_xor(mx, 4));
        float e0 = __expf(s0 - mx), e1 = __expf(s1 - mx);
        float e2 = (j == 0) ? __expf(s2 - mx) : 0.f;
        float ssum = e0 + e1 + e2;
        ssum += __shfl_xor(ssum, 1);
        ssum += __shfl_xor(ssum, 2);
        ssum += __shfl_xor(ssum, 4);
        float inv = 1.f / ssum;
        ao[r][q * 17 + j] = e0 * inv;
        ao[r][q * 17 + j + 8] = e1 * inv;
        if (j == 0) ao[r][q * 17 + 16] = e2 * inv;
    }
    __syncthreads();

    // ---------- Phase E: pooled + LayerNorm, both rows ----------
    #pragma unroll
    for (int r = 0; r < 2; ++r) {
        const int q = lane >> 3, dq = lane & 7;
        float4 acc = {0,0,0,0};
        #pragma unroll
        for (int gg = 0; gg < 17; ++gg) {
            float w = ao[r][q * 17 + gg];
            fma4(acc, w, *(float4*)&enc[r][gg * 36 + dq * 4]);
        }
        float sv = (acc.x + acc.y) + (acc.z + acc.w);
        sv += __shfl_xor(sv, 1); sv += __shfl_xor(sv, 2);
        sv += __shfl_xor(sv, 4); sv += __shfl_xor(sv, 8);
        float mu = sv * 0.015625f;
        float4 d;
        d.x = acc.x - mu; d.y = acc.y - mu; d.z = acc.z - mu; d.w = acc.w - mu;
        float v = (d.x*d.x + d.y*d.y) + (d.z*d.z + d.w*d.w);
        v += __shfl_xor(v, 1); v += __shfl_xor(v, 2);
        v += __shfl_xor(v, 4); v += __shfl_xor(v, 8);
        float rs = rsqrtf(v * 0.015625f + 1e-5f);
        float4 gam = ld4(ln_g + lane * 4);
        float4 bet = ld4(ln_b + lane * 4);
        float4 res;
        res.x = d.x*rs*gam.x + bet.x; res.y = d.y*rs*gam.y + bet.y;
        res.z = d.z*rs*gam.z + bet.z; res.w = d.w*rs*gam.w + bet.w;
        *(float4*)&hist[(size_t)(b0 + r) * 256 + lane * 4] = res;
    }
}

// ---------------- Kernel 2: backbone + per-target heads ----------------
// 16 rows per block, 256 threads. Measured-best (~32 us) b128 version.
__global__ __launch_bounds__(256) void backbone_kernel(
    const float* __restrict__ x_static,
    const float* __restrict__ W1, const float* __restrict__ b1,
    const float* __restrict__ g1, const float* __restrict__ be1,
    const float* __restrict__ m1, const float* __restrict__ v1,
    const float* __restrict__ W2, const float* __restrict__ b2,
    const float* __restrict__ g2, const float* __restrict__ be2,
    const float* __restrict__ m2, const float* __restrict__ v2,
    const float* __restrict__ Wh1, const float* __restrict__ bh1,
    const float* __restrict__ Wh2, const float* __restrict__ bh2,
    const float* __restrict__ hist, float* __restrict__ out)
{
    __shared__ float s_x[16 * 64];
    __shared__ float s_z1[16 * 256];
    __shared__ float s_z2[16 * 132];

    const int tid = threadIdx.x;
    const int row0 = blockIdx.x * 16;

    *(float4*)&s_x[tid * 4] = ld4(x_static + (size_t)row0 * 64 + tid * 4);
    __syncthreads();

    {
        const int col = tid;
        float acc[16];
        #pragma unroll
        for (int r = 0; r < 16; ++r) acc[r] = 0.f;
        for (int k4 = 0; k4 < 16; ++k4) {
            float w0 = W1[(k4 * 4 + 0) * 256 + col];
            float w1 = W1[(k4 * 4 + 1) * 256 + col];
            float w2 = W1[(k4 * 4 + 2) * 256 + col];
            float w3 = W1[(k4 * 4 + 3) * 256 + col];
            #pragma unroll
            for (int r = 0; r < 16; ++r) {
                float4 xv = *(float4*)&s_x[r * 64 + k4 * 4];
                acc[r] += xv.x * w0 + xv.y * w1 + xv.z * w2 + xv.w * w3;
            }
        }
        float sc = rsqrtf(v1[col] + 1e-5f) * g1[col];
        float off = b1[col] - m1[col];
        float bb = be1[col];
        #pragma unroll
        for (int r = 0; r < 16; ++r)
            s_z1[r * 256 + col] = fmaxf((acc[r] + off) * sc + bb, 0.f);
    }
    __syncthreads();

    {
        const int col = tid & 127;
        const int r0 = (tid >> 7) * 8;
        float acc[8];
        #pragma unroll
        for (int r = 0; r < 8; ++r) acc[r] = 0.f;
        for (int k4 = 0; k4 < 64; ++k4) {
            float w0 = W2[(k4 * 4 + 0) * 128 + col];
            float w1 = W2[(k4 * 4 + 1) * 128 + col];
            float w2 = W2[(k4 * 4 + 2) * 128 + col];
            float w3 = W2[(k4 * 4 + 3) * 128 + col];
            #pragma unroll
            for (int r = 0; r < 8; ++r) {
                float4 zv = *(float4*)&s_z1[(r0 + r) * 256 + k4 * 4];
                acc[r] += zv.x * w0 + zv.y * w1 + zv.z * w2 + zv.w * w3;
            }
        }
        float sc = rsqrtf(v2[col] + 1e-5f) * g2[col];
        float off = b2[col] - m2[col];
        float bb = be2[col];
        #pragma unroll
        for (int r = 0; r < 8; ++r)
            s_z2[(r0 + r) * 132 + col] = fmaxf((acc[r] + off) * sc + bb, 0.f);
    }
    __syncthreads();

    {
        const int p = tid >> 2;
        const int gl = tid & 3;
        const int row = p >> 2;
        const int tgt = p & 3;
        const int j0 = gl * 8;

        float acc[8];
        #pragma unroll
        for (int j = 0; j < 8; ++j) acc[j] = bh1[tgt * 32 + j0 + j];

        const float* w1p = Wh1 + (size_t)tgt * 192 * 32 + j0;
        for (int d4 = 0; d4 < 32; ++d4) {
            float4 zv = *(float4*)&s_z2[row * 132 + d4 * 4];
            #pragma unroll
            for (int c = 0; c < 4; ++c) {
                float v = (c == 0) ? zv.x : (c == 1) ? zv.y : (c == 2) ? zv.z : zv.w;
                float4 a = ld4(w1p + (d4 * 4 + c) * 32);
                float4 bq = ld4(w1p + (d4 * 4 + c) * 32 + 4);
                acc[0] += v * a.x;  acc[1] += v * a.y;  acc[2] += v * a.z;  acc[3] += v * a.w;
                acc[4] += v * bq.x; acc[5] += v * bq.y; acc[6] += v * bq.z; acc[7] += v * bq.w;
            }
        }
        const float* hp = hist + (size_t)(row0 + row) * 256 + tgt * 64;
        const float* w1q = w1p + 128 * 32;
        for (int d4 = 0; d4 < 16; ++d4) {
            float4 hv = ld4(hp + d4 * 4);
            #pragma unroll
            for (int c = 0; c < 4; ++c) {
                float v = (c == 0) ? hv.x : (c == 1) ? hv.y : (c == 2) ? hv.z : hv.w;
                float4 a = ld4(w1q + (d4 * 4 + c) * 32);
                float4 bq = ld4(w1q + (d4 * 4 + c) * 32 + 4);
                acc[0] += v * a.x;  acc[1] += v * a.y;  acc[2] += v * a.z;  acc[3] += v * a.w;
                acc[4] += v * bq.x; acc[5] += v * bq.y; acc[6] += v * bq.z; acc[7] += v * bq.w;
            }
        }
        float ps = 0.f;
        #pragma unroll
        for (int j = 0; j < 8; ++j) ps += fmaxf(acc[j], 0.f) * Wh2[tgt * 32 + j0 + j];
        ps += __shfl_xor(ps, 1);
        ps += __shfl_xor(ps, 2);
        if (gl == 0) out[(size_t)(row0 + row) * 4 + tgt] = fmaxf(ps + bh2[tgt], 0.f);
    }
}

extern "C" void kernel_launch(void* const* d_in, const int* in_sizes, int n_in,
                              void* d_out, int out_size, void* d_ws, size_t ws_size,
                              hipStream_t stream) {
    const float* x_static = (const float*)d_in[0];
    const float* x_kicks  = (const float*)d_in[1];
    const float* W_ke     = (const float*)d_in[2];
    const float* b_ke     = (const float*)d_in[3];
    const float* q_inner  = (const float*)d_in[4];
    const float* W_ge     = (const float*)d_in[5];
    const float* b_ge     = (const float*)d_in[6];
    const float* pos_emb  = (const float*)d_in[7];
    const float* q_outer  = (const float*)d_in[8];
    const float* log_temp = (const float*)d_in[9];
    const float* ln_g     = (const float*)d_in[10];
    const float* ln_b     = (const float*)d_in[11];
    const float* W1       = (const float*)d_in[12];
    const float* b1       = (const float*)d_in[13];
    const float* g1       = (const float*)d_in[14];
    const float* be1      = (const float*)d_in[15];
    const float* m1       = (const float*)d_in[16];
    const float* v1       = (const float*)d_in[17];
    const float* W2       = (const float*)d_in[18];
    const float* b2       = (const float*)d_in[19];
    const float* g2       = (const float*)d_in[20];
    const float* be2      = (const float*)d_in[21];
    const float* m2       = (const float*)d_in[22];
    const float* v2       = (const float*)d_in[23];
    const float* Wh1      = (const float*)d_in[24];
    const float* bh1      = (const float*)d_in[25];
    const float* Wh2      = (const float*)d_in[26];
    const float* bh2      = (const float*)d_in[27];
    const int* outer_mask = (const int*)d_in[28];
    const int* inner_mask = (const int*)d_in[29];

    float* hist = (float*)d_ws;           // 16384 * 256 floats = 16.8 MB
    float* out  = (float*)d_out;

    hist_kernel<<<16384 / 2, 64, 0, stream>>>(
        x_kicks, W_ke, b_ke, q_inner, W_ge, b_ge, pos_emb, q_outer,
        log_temp, ln_g, ln_b, outer_mask, inner_mask, hist);

    backbone_kernel<<<16384 / 16, 256, 0, stream>>>(
        x_static, W1, b1, g1, be1, m1, v1, W2, b2, g2, be2, m2, v2,
        Wh1, bh1, Wh2, bh2, hist, out);
}